// Round 1
// baseline (825.565 us; speedup 1.0000x reference)
//
#include <hip/hip_runtime.h>
#include <math.h>

#define NB 4
#define NC 256
#define NH 256
#define NW 256
#define NPIX 65536
#define NSP 1024
#define HID 128
#define OUTD 64

// ---------------- counts: histogram of superpixel ids per image ----------------
__global__ __launch_bounds__(256) void count_kernel(const int* __restrict__ idx,
                                                    float* __restrict__ counts) {
    __shared__ unsigned cnt[NSP];
    int b = blockIdx.x;
    int tid = threadIdx.x;
    for (int s = tid; s < NSP; s += 256) cnt[s] = 0u;
    __syncthreads();
    const int4* idx4 = (const int4*)(idx + b * NPIX);
    for (int it = 0; it < NPIX / 1024; ++it) {
        int4 s4 = idx4[it * 256 + tid];
        atomicAdd(&cnt[s4.x], 1u);
        atomicAdd(&cnt[s4.y], 1u);
        atomicAdd(&cnt[s4.z], 1u);
        atomicAdd(&cnt[s4.w], 1u);
    }
    __syncthreads();
    for (int s = tid; s < NSP; s += 256) counts[b * NSP + s] = (float)cnt[s];
}

// ---------------- scatter-sum: one block per (channel, image), LDS bins --------
__global__ __launch_bounds__(256) void agg_kernel(const float* __restrict__ feat,
                                                  const int* __restrict__ idx,
                                                  float* __restrict__ sp_sum) {
    __shared__ float lsum[NSP];
    int c = blockIdx.x, b = blockIdx.y;
    int tid = threadIdx.x;
    for (int s = tid; s < NSP; s += 256) lsum[s] = 0.f;
    __syncthreads();
    const int4* idx4 = (const int4*)(idx + b * NPIX);
    const float4* f4 = (const float4*)(feat + ((size_t)b * NC + c) * NPIX);
    for (int it = 0; it < 64; ++it) {
        int4 s4 = idx4[it * 256 + tid];
        float4 v = f4[it * 256 + tid];
        atomicAdd(&lsum[s4.x], v.x);
        atomicAdd(&lsum[s4.y], v.y);
        atomicAdd(&lsum[s4.z], v.z);
        atomicAdd(&lsum[s4.w], v.w);
    }
    __syncthreads();
    for (int s = tid; s < NSP; s += 256)
        sp_sum[((size_t)b * NSP + s) * NC + c] = lsum[s];
}

// ---------------- binary adjacency (idempotent 1.0 stores) + identity ----------
__global__ __launch_bounds__(256) void adj_kernel(const int* __restrict__ idx,
                                                  float* __restrict__ adj) {
    const int PAIRS = 65280;              // 256*255 per orientation
    const int PERB = 2 * PAIRS + NSP;     // 131584
    int i = blockIdx.x * 256 + threadIdx.x;
    if (i >= NB * PERB) return;
    int b = i / PERB;
    int r = i % PERB;
    float* A = adj + (size_t)b * NSP * NSP;
    const int* id = idx + b * NPIX;
    if (r >= 2 * PAIRS) {
        int s = r - 2 * PAIRS;
        A[s * NSP + s] = 1.0f;            // eye
        return;
    }
    int p1, p2;
    if (r < PAIRS) {                      // horizontal neighbors
        int row = r / 255, col = r % 255;
        p1 = row * NW + col; p2 = p1 + 1;
    } else {                              // vertical neighbors
        int rv = r - PAIRS;               // rv = row*256+col, row<255
        p1 = rv; p2 = rv + NW;
    }
    int s1 = id[p1], s2 = id[p2];
    if (s1 != s2) {
        A[s1 * NSP + s2] = 1.0f;
        A[s2 * NSP + s1] = 1.0f;
    }
}

// ---------------- deg_inv[row] = 1/sqrt(rowsum) --------------------------------
__global__ __launch_bounds__(256) void deg_kernel(const float* __restrict__ adj,
                                                  float* __restrict__ deg_inv) {
    int row = blockIdx.x;                 // 0 .. NB*NSP-1
    int tid = threadIdx.x;
    const float4* a4 = (const float4*)(adj + (size_t)row * NSP);
    float4 v = a4[tid];
    float s = v.x + v.y + v.z + v.w;
    for (int off = 32; off > 0; off >>= 1) s += __shfl_down(s, off, 64);
    __shared__ float wsum[4];
    if ((tid & 63) == 0) wsum[tid >> 6] = s;
    __syncthreads();
    if (tid == 0) deg_inv[row] = 1.0f / sqrtf(wsum[0] + wsum[1] + wsum[2] + wsum[3]);
}

// ---------------- sp_feat = (sum/count) * deg_inv[j], in place -----------------
__global__ __launch_bounds__(256) void finalize_kernel(float* __restrict__ sp_sum,
                                                       const float* __restrict__ counts,
                                                       const float* __restrict__ deg_inv) {
    int f = blockIdx.x * 256 + threadIdx.x;   // float4 index
    int bj = f / (NC / 4);
    float cnt = counts[bj];
    float scale = cnt > 0.f ? deg_inv[bj] / cnt : 0.f;
    float4* p = (float4*)sp_sum;
    float4 v = p[f];
    v.x *= scale; v.y *= scale; v.z *= scale; v.w *= scale;
    p[f] = v;
}

// ---------------- x = deg_inv[i] * (adj_bin @ sp_feat_scaled) ------------------
__global__ __launch_bounds__(256) void conv_kernel(const float* __restrict__ adj,
                                                   const float* __restrict__ spf,
                                                   const float* __restrict__ deg_inv,
                                                   float* __restrict__ x) {
    __shared__ float As[16 * 68];   // [k][m], padded
    __shared__ float Bs[16 * 64];   // [k][n]
    int b = blockIdx.z;
    int m0 = blockIdx.y * 64, n0 = blockIdx.x * 64;
    int tid = threadIdx.x;
    int ty = tid >> 4, tx = tid & 15;
    const float* A = adj + (size_t)b * NSP * NSP;
    const float* Bm = spf + (size_t)b * NSP * NC;
    float acc[4][4] = {};
    int ar = tid >> 2, aq = tid & 3;
    int br = tid >> 4, bq = tid & 15;
    for (int kt = 0; kt < 64; ++kt) {
        int k0 = kt * 16;
        float4 av = *(const float4*)&A[(size_t)(m0 + ar) * NSP + k0 + aq * 4];
        float4 bv = *(const float4*)&Bm[(size_t)(k0 + br) * NC + n0 + bq * 4];
        __syncthreads();
        As[(aq * 4 + 0) * 68 + ar] = av.x;
        As[(aq * 4 + 1) * 68 + ar] = av.y;
        As[(aq * 4 + 2) * 68 + ar] = av.z;
        As[(aq * 4 + 3) * 68 + ar] = av.w;
        *(float4*)&Bs[br * 64 + bq * 4] = bv;
        __syncthreads();
        #pragma unroll
        for (int k = 0; k < 16; ++k) {
            float4 a4 = *(const float4*)&As[k * 68 + ty * 4];
            float4 b4 = *(const float4*)&Bs[k * 64 + tx * 4];
            float am[4] = {a4.x, a4.y, a4.z, a4.w};
            float bn[4] = {b4.x, b4.y, b4.z, b4.w};
            #pragma unroll
            for (int i = 0; i < 4; ++i)
                #pragma unroll
                for (int j = 0; j < 4; ++j)
                    acc[i][j] = fmaf(am[i], bn[j], acc[i][j]);
        }
    }
    #pragma unroll
    for (int i = 0; i < 4; ++i) {
        int row = m0 + ty * 4 + i;
        float di = deg_inv[b * NSP + row];
        float4 o = {acc[i][0] * di, acc[i][1] * di, acc[i][2] * di, acc[i][3] * di};
        *(float4*)&x[((size_t)b * NSP + row) * NC + n0 + tx * 4] = o;
    }
}

// ---------------- fused encoder: x -> h1 -> h2 -> z1,z2 (row-normalized) -------
__global__ __launch_bounds__(256) void encoder_kernel(
    const float* __restrict__ x,
    const float* __restrict__ W1, const float* __restrict__ b1,
    const float* __restrict__ W2, const float* __restrict__ b2,
    const float* __restrict__ Wp1, const float* __restrict__ bp1,
    const float* __restrict__ Wp2, const float* __restrict__ bp2,
    float* __restrict__ z1g, float* __restrict__ z2g) {
    __shared__ float xs[16 * 260];
    __shared__ float h1s[16 * 132];
    __shared__ float h2s[16 * 132];
    __shared__ float red1[16 * 17], red2[16 * 17];
    __shared__ float inv1[16], inv2[16];
    int blk = blockIdx.x;
    int b = blk >> 6;
    int r0 = (blk & 63) * 16;
    int tid = threadIdx.x;
    for (int it = 0; it < 4; ++it) {
        int fl = it * 256 + tid;
        int row = fl >> 6, c4 = fl & 63;
        float4 v = *(const float4*)&x[((size_t)b * NSP + r0 + row) * NC + c4 * 4];
        *(float4*)&xs[row * 260 + c4 * 4] = v;
    }
    __syncthreads();
    int r = tid & 15, tc = tid >> 4;   // 16 rows x 16 thread-cols
    // h1 = relu(x @ W1^T + b1), 8 outputs per thread
    float acc[8] = {};
    for (int k4 = 0; k4 < 64; ++k4) {
        float4 xv = *(const float4*)&xs[r * 260 + k4 * 4];
        #pragma unroll
        for (int u = 0; u < 8; ++u) {
            int n = tc * 8 + u;
            float4 wv = *(const float4*)&W1[n * 256 + k4 * 4];
            acc[u] += xv.x * wv.x + xv.y * wv.y + xv.z * wv.z + xv.w * wv.w;
        }
    }
    #pragma unroll
    for (int u = 0; u < 8; ++u) {
        int n = tc * 8 + u;
        h1s[r * 132 + n] = fmaxf(acc[u] + b1[n], 0.f);
    }
    __syncthreads();
    // h2 = relu(h1 @ W2^T + b2)
    float acc2[8] = {};
    for (int k4 = 0; k4 < 32; ++k4) {
        float4 hv = *(const float4*)&h1s[r * 132 + k4 * 4];
        #pragma unroll
        for (int u = 0; u < 8; ++u) {
            int n = tc * 8 + u;
            float4 wv = *(const float4*)&W2[n * 128 + k4 * 4];
            acc2[u] += hv.x * wv.x + hv.y * wv.y + hv.z * wv.z + hv.w * wv.w;
        }
    }
    #pragma unroll
    for (int u = 0; u < 8; ++u) {
        int n = tc * 8 + u;
        h2s[r * 132 + n] = fmaxf(acc2[u] + b2[n], 0.f);
    }
    __syncthreads();
    // z1 = h2 @ Wp1^T + bp1 ; z2 = h2 @ Wp2^T + bp2 ; then row-normalize
    float az1[4] = {}, az2[4] = {};
    for (int k4 = 0; k4 < 32; ++k4) {
        float4 hv = *(const float4*)&h2s[r * 132 + k4 * 4];
        #pragma unroll
        for (int u = 0; u < 4; ++u) {
            int n = tc * 4 + u;
            float4 w1v = *(const float4*)&Wp1[n * 128 + k4 * 4];
            float4 w2v = *(const float4*)&Wp2[n * 128 + k4 * 4];
            az1[u] += hv.x * w1v.x + hv.y * w1v.y + hv.z * w1v.z + hv.w * w1v.w;
            az2[u] += hv.x * w2v.x + hv.y * w2v.y + hv.z * w2v.z + hv.w * w2v.w;
        }
    }
    float ss1 = 0.f, ss2 = 0.f;
    #pragma unroll
    for (int u = 0; u < 4; ++u) {
        int n = tc * 4 + u;
        az1[u] += bp1[n]; az2[u] += bp2[n];
        ss1 += az1[u] * az1[u];
        ss2 += az2[u] * az2[u];
    }
    red1[r * 17 + tc] = ss1;
    red2[r * 17 + tc] = ss2;
    __syncthreads();
    if (tid < 16) {
        float s1 = 0.f, s2 = 0.f;
        for (int t = 0; t < 16; ++t) { s1 += red1[tid * 17 + t]; s2 += red2[tid * 17 + t]; }
        inv1[tid] = 1.0f / sqrtf(s1);
        inv2[tid] = 1.0f / sqrtf(s2);
    }
    __syncthreads();
    float i1 = inv1[r], i2 = inv2[r];
    float4 o1 = {az1[0] * i1, az1[1] * i1, az1[2] * i1, az1[3] * i1};
    float4 o2 = {az2[0] * i2, az2[1] * i2, az2[2] * i2, az2[3] * i2};
    *(float4*)&z1g[((size_t)b * NSP + r0 + r) * OUTD + tc * 4] = o1;
    *(float4*)&z2g[((size_t)b * NSP + r0 + r) * OUTD + tc * 4] = o2;
}

// ---------------- InfoNCE rows: loss_i = -sim_ii + log(sum_j exp(sim_ij)) ------
// |sim| <= 10 so exp cannot overflow fp32 -> no max-subtraction needed.
__global__ __launch_bounds__(256) void infonce_kernel(const float* __restrict__ z1g,
                                                      const float* __restrict__ z2g,
                                                      float* __restrict__ row_loss) {
    __shared__ float z1s[16 * 68];
    __shared__ float z2s[16 * 68];
    __shared__ float reds[16 * 17];
    __shared__ float diag[16];
    int blk = blockIdx.x;
    int b = blk >> 6;
    int i0 = (blk & 63) * 16;
    int tid = threadIdx.x;
    int lrow = tid >> 4, lc4 = tid & 15;
    float4 v = *(const float4*)&z1g[((size_t)b * NSP + i0 + lrow) * OUTD + lc4 * 4];
    *(float4*)&z1s[lrow * 68 + lc4 * 4] = v;
    int ti = tid >> 4, tj = tid & 15;
    float lsum = 0.f;
    for (int jt = 0; jt < 64; ++jt) {
        __syncthreads();
        float4 w = *(const float4*)&z2g[((size_t)b * NSP + jt * 16 + lrow) * OUTD + lc4 * 4];
        *(float4*)&z2s[lrow * 68 + lc4 * 4] = w;
        __syncthreads();
        float dot = 0.f;
        #pragma unroll
        for (int k4 = 0; k4 < 16; ++k4) {
            float4 a = *(const float4*)&z1s[ti * 68 + k4 * 4];
            float4 bb = *(const float4*)&z2s[tj * 68 + k4 * 4];
            dot += a.x * bb.x + a.y * bb.y + a.z * bb.z + a.w * bb.w;
        }
        float sim = dot * 10.0f;           // 1/TEMPERATURE
        lsum += expf(sim);
        if (jt * 16 + tj == i0 + ti) diag[ti] = sim;
    }
    reds[ti * 17 + tj] = lsum;
    __syncthreads();
    if (tid < 16) {
        float tot = 0.f;
        for (int t = 0; t < 16; ++t) tot += reds[tid * 17 + t];
        row_loss[b * NSP + i0 + tid] = -diag[tid] + logf(tot);
    }
}

// ---------------- final mean over 4096 rows ------------------------------------
__global__ __launch_bounds__(256) void reduce_kernel(const float* __restrict__ row_loss,
                                                     float* __restrict__ out) {
    int tid = threadIdx.x;
    float s = 0.f;
    for (int i = tid; i < NB * NSP; i += 256) s += row_loss[i];
    for (int off = 32; off > 0; off >>= 1) s += __shfl_down(s, off, 64);
    __shared__ float wsum[4];
    if ((tid & 63) == 0) wsum[tid >> 6] = s;
    __syncthreads();
    if (tid == 0) out[0] = (wsum[0] + wsum[1] + wsum[2] + wsum[3]) * (1.0f / (NB * NSP));
}

extern "C" void kernel_launch(void* const* d_in, const int* in_sizes, int n_in,
                              void* d_out, int out_size, void* d_ws, size_t ws_size,
                              hipStream_t stream) {
    const float* feat = (const float*)d_in[0];
    const int* idx = (const int*)d_in[1];
    const float* W1 = (const float*)d_in[2];
    const float* b1 = (const float*)d_in[3];
    const float* W2 = (const float*)d_in[4];
    const float* b2 = (const float*)d_in[5];
    const float* Wp1 = (const float*)d_in[6];
    const float* bp1 = (const float*)d_in[7];
    const float* Wp2 = (const float*)d_in[8];
    const float* bp2 = (const float*)d_in[9];

    float* ws = (float*)d_ws;
    size_t off = 0;
    float* sp_sum = ws + off;  off += (size_t)NB * NSP * NC;    // 1,048,576
    float* counts = ws + off;  off += (size_t)NB * NSP;         // 4,096
    float* adj    = ws + off;  off += (size_t)NB * NSP * NSP;   // 4,194,304
    float* deg_inv= ws + off;  off += (size_t)NB * NSP;
    float* x      = ws + off;  off += (size_t)NB * NSP * NC;
    float* z1g    = ws + off;  off += (size_t)NB * NSP * OUTD;
    float* z2g    = ws + off;  off += (size_t)NB * NSP * OUTD;
    float* row_loss = ws + off; off += (size_t)NB * NSP;
    // total ~27.3 MB of workspace

    // only adj needs zero-init (1.0 stores are sparse); everything else is fully overwritten
    hipMemsetAsync(adj, 0, (size_t)NB * NSP * NSP * sizeof(float), stream);

    count_kernel<<<NB, 256, 0, stream>>>(idx, counts);
    agg_kernel<<<dim3(NC, NB), 256, 0, stream>>>(feat, idx, sp_sum);
    int total_adj = NB * (2 * 65280 + NSP);
    adj_kernel<<<(total_adj + 255) / 256, 256, 0, stream>>>(idx, adj);
    deg_kernel<<<NB * NSP, 256, 0, stream>>>(adj, deg_inv);
    finalize_kernel<<<(NB * NSP * NC / 4) / 256, 256, 0, stream>>>(sp_sum, counts, deg_inv);
    conv_kernel<<<dim3(NC / 64, NSP / 64, NB), 256, 0, stream>>>(adj, sp_sum, deg_inv, x);
    encoder_kernel<<<NB * 64, 256, 0, stream>>>(x, W1, b1, W2, b2, Wp1, bp1, Wp2, bp2, z1g, z2g);
    infonce_kernel<<<NB * 64, 256, 0, stream>>>(z1g, z2g, row_loss);
    reduce_kernel<<<1, 256, 0, stream>>>(row_loss, (float*)d_out);
}

// Round 2
// 674.406 us; speedup vs baseline: 1.2241x; 1.2241x over previous
//
#include <hip/hip_runtime.h>
#include <math.h>

#define NB 4
#define NC 256
#define NH 256
#define NW 256
#define NPIX 65536
#define NSP 1024
#define HID 128
#define OUTD 64

// ---------------- hist: LDS histogram per 1024-pixel tile -> global merge -----
__global__ __launch_bounds__(256) void hist_kernel(const int* __restrict__ idx,
                                                   unsigned* __restrict__ counts_u) {
    __shared__ unsigned cnt[NSP];
    int b = blockIdx.y;
    int tid = threadIdx.x;
    for (int s = tid; s < NSP; s += 256) cnt[s] = 0u;
    __syncthreads();
    const int4* idx4 = (const int4*)(idx + b * NPIX + blockIdx.x * 1024);
    int4 s4 = idx4[tid];
    atomicAdd(&cnt[s4.x], 1u);
    atomicAdd(&cnt[s4.y], 1u);
    atomicAdd(&cnt[s4.z], 1u);
    atomicAdd(&cnt[s4.w], 1u);
    __syncthreads();
    for (int s = tid; s < NSP; s += 256)
        if (cnt[s]) atomicAdd(&counts_u[b * NSP + s], cnt[s]);
}

// ---------------- scan: exclusive prefix over 1024 bins per image --------------
__global__ __launch_bounds__(256) void scan_kernel(const unsigned* __restrict__ counts_u,
                                                   unsigned* __restrict__ offsets,
                                                   unsigned* __restrict__ cursor) {
    int b = blockIdx.x;
    int tid = threadIdx.x;
    __shared__ unsigned v[256];
    unsigned c0 = counts_u[b * NSP + tid * 4 + 0];
    unsigned c1 = counts_u[b * NSP + tid * 4 + 1];
    unsigned c2 = counts_u[b * NSP + tid * 4 + 2];
    unsigned c3 = counts_u[b * NSP + tid * 4 + 3];
    v[tid] = c0 + c1 + c2 + c3;
    __syncthreads();
    for (int off = 1; off < 256; off <<= 1) {
        unsigned t = (tid >= off) ? v[tid - off] : 0u;
        __syncthreads();
        v[tid] += t;
        __syncthreads();
    }
    unsigned base = tid ? v[tid - 1] : 0u;
    unsigned o0 = base, o1 = base + c0, o2 = base + c0 + c1, o3 = base + c0 + c1 + c2;
    offsets[b * (NSP + 1) + tid * 4 + 0] = o0;
    offsets[b * (NSP + 1) + tid * 4 + 1] = o1;
    offsets[b * (NSP + 1) + tid * 4 + 2] = o2;
    offsets[b * (NSP + 1) + tid * 4 + 3] = o3;
    cursor[b * NSP + tid * 4 + 0] = o0;
    cursor[b * NSP + tid * 4 + 1] = o1;
    cursor[b * NSP + tid * 4 + 2] = o2;
    cursor[b * NSP + tid * 4 + 3] = o3;
    if (tid == 255) offsets[b * (NSP + 1) + NSP] = v[255];
}

// ---------------- rank: sorted position of each pixel (two-level atomics) ------
__global__ __launch_bounds__(256) void rank_kernel(const int* __restrict__ idx,
                                                   unsigned* __restrict__ cursor,
                                                   int* __restrict__ rank) {
    __shared__ unsigned lcnt[NSP];
    __shared__ unsigned base[NSP];
    int b = blockIdx.y;
    int tid = threadIdx.x;
    for (int s = tid; s < NSP; s += 256) lcnt[s] = 0u;
    __syncthreads();
    const int4* idx4 = (const int4*)(idx + b * NPIX + blockIdx.x * 1024);
    int4 s4 = idx4[tid];
    unsigned r0 = atomicAdd(&lcnt[s4.x], 1u);
    unsigned r1 = atomicAdd(&lcnt[s4.y], 1u);
    unsigned r2 = atomicAdd(&lcnt[s4.z], 1u);
    unsigned r3 = atomicAdd(&lcnt[s4.w], 1u);
    __syncthreads();
    for (int s = tid; s < NSP; s += 256) {
        unsigned c = lcnt[s];
        base[s] = c ? atomicAdd(&cursor[b * NSP + s], c) : 0u;
    }
    __syncthreads();
    int p = b * NPIX + blockIdx.x * 1024 + tid * 4;
    rank[p + 0] = (int)(base[s4.x] + r0);
    rank[p + 1] = (int)(base[s4.y] + r1);
    rank[p + 2] = (int)(base[s4.z] + r2);
    rank[p + 3] = (int)(base[s4.w] + r3);
}

// ---------------- transpose+permute: feat[C][HW] -> featP[rank[p]][C] ----------
#define TPAD 260
__global__ __launch_bounds__(256) void transpose_kernel(const float* __restrict__ feat,
                                                        const int* __restrict__ rank,
                                                        float* __restrict__ featP, int b) {
    __shared__ float tile[32 * TPAD];
    __shared__ int rk[32];
    int p0 = blockIdx.x * 32;
    int tid = threadIdx.x;
    if (tid < 32) rk[tid] = rank[b * NPIX + p0 + tid];
    int p4 = tid & 7;        // 8 float4 groups -> 32 pixels
    int cbase = tid >> 3;    // 32 channels per pass
    #pragma unroll
    for (int pass = 0; pass < 8; ++pass) {
        int c = pass * 32 + cbase;
        float4 v = *(const float4*)&feat[((size_t)(b * NC + c)) * NPIX + p0 + p4 * 4];
        tile[(p4 * 4 + 0) * TPAD + c] = v.x;
        tile[(p4 * 4 + 1) * TPAD + c] = v.y;
        tile[(p4 * 4 + 2) * TPAD + c] = v.z;
        tile[(p4 * 4 + 3) * TPAD + c] = v.w;
    }
    __syncthreads();
    int c4 = tid & 63;
    int pi0 = tid >> 6;      // 4 pixels per pass
    #pragma unroll
    for (int pass = 0; pass < 8; ++pass) {
        int pi = pass * 4 + pi0;
        float4 v = *(const float4*)&tile[pi * TPAD + c4 * 4];
        *(float4*)&featP[((size_t)rk[pi]) * NC + c4 * 4] = v;
    }
}

// ---------------- segmented sum over sorted rows + mean + deg_inv scale --------
__global__ __launch_bounds__(256) void segsum_kernel(const float* __restrict__ featP,
                                                     const unsigned* __restrict__ offsets,
                                                     const float* __restrict__ deg_inv,
                                                     float* __restrict__ sp, int b) {
    int s = blockIdx.x;
    int c = threadIdx.x;
    unsigned j0 = offsets[b * (NSP + 1) + s];
    unsigned j1 = offsets[b * (NSP + 1) + s + 1];
    float a0 = 0.f, a1 = 0.f, a2 = 0.f, a3 = 0.f;
    unsigned j = j0;
    for (; j + 4 <= j1; j += 4) {
        a0 += featP[(size_t)(j + 0) * NC + c];
        a1 += featP[(size_t)(j + 1) * NC + c];
        a2 += featP[(size_t)(j + 2) * NC + c];
        a3 += featP[(size_t)(j + 3) * NC + c];
    }
    for (; j < j1; ++j) a0 += featP[(size_t)j * NC + c];
    float acc = (a0 + a1) + (a2 + a3);
    unsigned cnt = j1 - j0;
    float scale = cnt ? deg_inv[b * NSP + s] / (float)cnt : 0.f;
    sp[((size_t)b * NSP + s) * NC + c] = acc * scale;
}

// ---------------- binary adjacency (idempotent 1.0 stores) + identity ----------
__global__ __launch_bounds__(256) void adj_kernel(const int* __restrict__ idx,
                                                  float* __restrict__ adj) {
    const int PAIRS = 65280;              // 256*255 per orientation
    const int PERB = 2 * PAIRS + NSP;     // 131584
    int i = blockIdx.x * 256 + threadIdx.x;
    if (i >= NB * PERB) return;
    int b = i / PERB;
    int r = i % PERB;
    float* A = adj + (size_t)b * NSP * NSP;
    const int* id = idx + b * NPIX;
    if (r >= 2 * PAIRS) {
        int s = r - 2 * PAIRS;
        A[s * NSP + s] = 1.0f;            // eye
        return;
    }
    int p1, p2;
    if (r < PAIRS) {                      // horizontal neighbors
        int row = r / 255, col = r % 255;
        p1 = row * NW + col; p2 = p1 + 1;
    } else {                              // vertical neighbors
        int rv = r - PAIRS;
        p1 = rv; p2 = rv + NW;
    }
    int s1 = id[p1], s2 = id[p2];
    if (s1 != s2) {
        A[s1 * NSP + s2] = 1.0f;
        A[s2 * NSP + s1] = 1.0f;
    }
}

// ---------------- deg_inv[row] = 1/sqrt(rowsum) --------------------------------
__global__ __launch_bounds__(256) void deg_kernel(const float* __restrict__ adj,
                                                  float* __restrict__ deg_inv) {
    int row = blockIdx.x;                 // 0 .. NB*NSP-1
    int tid = threadIdx.x;
    const float4* a4 = (const float4*)(adj + (size_t)row * NSP);
    float4 v = a4[tid];
    float s = v.x + v.y + v.z + v.w;
    for (int off = 32; off > 0; off >>= 1) s += __shfl_down(s, off, 64);
    __shared__ float wsum[4];
    if ((tid & 63) == 0) wsum[tid >> 6] = s;
    __syncthreads();
    if (tid == 0) deg_inv[row] = 1.0f / sqrtf(wsum[0] + wsum[1] + wsum[2] + wsum[3]);
}

// ---------------- x = deg_inv[i] * (adj_bin @ sp_feat_scaled) ------------------
__global__ __launch_bounds__(256) void conv_kernel(const float* __restrict__ adj,
                                                   const float* __restrict__ spf,
                                                   const float* __restrict__ deg_inv,
                                                   float* __restrict__ x) {
    __shared__ float As[16 * 68];   // [k][m], padded
    __shared__ float Bs[16 * 64];   // [k][n]
    int b = blockIdx.z;
    int m0 = blockIdx.y * 64, n0 = blockIdx.x * 64;
    int tid = threadIdx.x;
    int ty = tid >> 4, tx = tid & 15;
    const float* A = adj + (size_t)b * NSP * NSP;
    const float* Bm = spf + (size_t)b * NSP * NC;
    float acc[4][4] = {};
    int ar = tid >> 2, aq = tid & 3;
    int br = tid >> 4, bq = tid & 15;
    for (int kt = 0; kt < 64; ++kt) {
        int k0 = kt * 16;
        float4 av = *(const float4*)&A[(size_t)(m0 + ar) * NSP + k0 + aq * 4];
        float4 bv = *(const float4*)&Bm[(size_t)(k0 + br) * NC + n0 + bq * 4];
        __syncthreads();
        As[(aq * 4 + 0) * 68 + ar] = av.x;
        As[(aq * 4 + 1) * 68 + ar] = av.y;
        As[(aq * 4 + 2) * 68 + ar] = av.z;
        As[(aq * 4 + 3) * 68 + ar] = av.w;
        *(float4*)&Bs[br * 64 + bq * 4] = bv;
        __syncthreads();
        #pragma unroll
        for (int k = 0; k < 16; ++k) {
            float4 a4 = *(const float4*)&As[k * 68 + ty * 4];
            float4 b4 = *(const float4*)&Bs[k * 64 + tx * 4];
            float am[4] = {a4.x, a4.y, a4.z, a4.w};
            float bn[4] = {b4.x, b4.y, b4.z, b4.w};
            #pragma unroll
            for (int i = 0; i < 4; ++i)
                #pragma unroll
                for (int j = 0; j < 4; ++j)
                    acc[i][j] = fmaf(am[i], bn[j], acc[i][j]);
        }
    }
    #pragma unroll
    for (int i = 0; i < 4; ++i) {
        int row = m0 + ty * 4 + i;
        float di = deg_inv[b * NSP + row];
        float4 o = {acc[i][0] * di, acc[i][1] * di, acc[i][2] * di, acc[i][3] * di};
        *(float4*)&x[((size_t)b * NSP + row) * NC + n0 + tx * 4] = o;
    }
}

// ---------------- fused encoder: x -> h1 -> h2 -> z1,z2 (row-normalized) -------
__global__ __launch_bounds__(256) void encoder_kernel(
    const float* __restrict__ x,
    const float* __restrict__ W1, const float* __restrict__ b1,
    const float* __restrict__ W2, const float* __restrict__ b2,
    const float* __restrict__ Wp1, const float* __restrict__ bp1,
    const float* __restrict__ Wp2, const float* __restrict__ bp2,
    float* __restrict__ z1g, float* __restrict__ z2g) {
    __shared__ float xs[16 * 260];
    __shared__ float h1s[16 * 132];
    __shared__ float h2s[16 * 132];
    __shared__ float red1[16 * 17], red2[16 * 17];
    __shared__ float inv1[16], inv2[16];
    int blk = blockIdx.x;
    int b = blk >> 6;
    int r0 = (blk & 63) * 16;
    int tid = threadIdx.x;
    for (int it = 0; it < 4; ++it) {
        int fl = it * 256 + tid;
        int row = fl >> 6, c4 = fl & 63;
        float4 v = *(const float4*)&x[((size_t)b * NSP + r0 + row) * NC + c4 * 4];
        *(float4*)&xs[row * 260 + c4 * 4] = v;
    }
    __syncthreads();
    int r = tid & 15, tc = tid >> 4;   // 16 rows x 16 thread-cols
    float acc[8] = {};
    for (int k4 = 0; k4 < 64; ++k4) {
        float4 xv = *(const float4*)&xs[r * 260 + k4 * 4];
        #pragma unroll
        for (int u = 0; u < 8; ++u) {
            int n = tc * 8 + u;
            float4 wv = *(const float4*)&W1[n * 256 + k4 * 4];
            acc[u] += xv.x * wv.x + xv.y * wv.y + xv.z * wv.z + xv.w * wv.w;
        }
    }
    #pragma unroll
    for (int u = 0; u < 8; ++u) {
        int n = tc * 8 + u;
        h1s[r * 132 + n] = fmaxf(acc[u] + b1[n], 0.f);
    }
    __syncthreads();
    float acc2[8] = {};
    for (int k4 = 0; k4 < 32; ++k4) {
        float4 hv = *(const float4*)&h1s[r * 132 + k4 * 4];
        #pragma unroll
        for (int u = 0; u < 8; ++u) {
            int n = tc * 8 + u;
            float4 wv = *(const float4*)&W2[n * 128 + k4 * 4];
            acc2[u] += hv.x * wv.x + hv.y * wv.y + hv.z * wv.z + hv.w * wv.w;
        }
    }
    #pragma unroll
    for (int u = 0; u < 8; ++u) {
        int n = tc * 8 + u;
        h2s[r * 132 + n] = fmaxf(acc2[u] + b2[n], 0.f);
    }
    __syncthreads();
    float az1[4] = {}, az2[4] = {};
    for (int k4 = 0; k4 < 32; ++k4) {
        float4 hv = *(const float4*)&h2s[r * 132 + k4 * 4];
        #pragma unroll
        for (int u = 0; u < 4; ++u) {
            int n = tc * 4 + u;
            float4 w1v = *(const float4*)&Wp1[n * 128 + k4 * 4];
            float4 w2v = *(const float4*)&Wp2[n * 128 + k4 * 4];
            az1[u] += hv.x * w1v.x + hv.y * w1v.y + hv.z * w1v.z + hv.w * w1v.w;
            az2[u] += hv.x * w2v.x + hv.y * w2v.y + hv.z * w2v.z + hv.w * w2v.w;
        }
    }
    float ss1 = 0.f, ss2 = 0.f;
    #pragma unroll
    for (int u = 0; u < 4; ++u) {
        int n = tc * 4 + u;
        az1[u] += bp1[n]; az2[u] += bp2[n];
        ss1 += az1[u] * az1[u];
        ss2 += az2[u] * az2[u];
    }
    red1[r * 17 + tc] = ss1;
    red2[r * 17 + tc] = ss2;
    __syncthreads();
    if (tid < 16) {
        float s1 = 0.f, s2 = 0.f;
        for (int t = 0; t < 16; ++t) { s1 += red1[tid * 17 + t]; s2 += red2[tid * 17 + t]; }
        inv1[tid] = 1.0f / sqrtf(s1);
        inv2[tid] = 1.0f / sqrtf(s2);
    }
    __syncthreads();
    float i1 = inv1[r], i2 = inv2[r];
    float4 o1 = {az1[0] * i1, az1[1] * i1, az1[2] * i1, az1[3] * i1};
    float4 o2 = {az2[0] * i2, az2[1] * i2, az2[2] * i2, az2[3] * i2};
    *(float4*)&z1g[((size_t)b * NSP + r0 + r) * OUTD + tc * 4] = o1;
    *(float4*)&z2g[((size_t)b * NSP + r0 + r) * OUTD + tc * 4] = o2;
}

// ---------------- InfoNCE rows: loss_i = -sim_ii + log(sum_j exp(sim_ij)) ------
__global__ __launch_bounds__(256) void infonce_kernel(const float* __restrict__ z1g,
                                                      const float* __restrict__ z2g,
                                                      float* __restrict__ row_loss) {
    __shared__ float z1s[16 * 68];
    __shared__ float z2s[16 * 68];
    __shared__ float reds[16 * 17];
    __shared__ float diag[16];
    int blk = blockIdx.x;
    int b = blk >> 6;
    int i0 = (blk & 63) * 16;
    int tid = threadIdx.x;
    int lrow = tid >> 4, lc4 = tid & 15;
    float4 v = *(const float4*)&z1g[((size_t)b * NSP + i0 + lrow) * OUTD + lc4 * 4];
    *(float4*)&z1s[lrow * 68 + lc4 * 4] = v;
    int ti = tid >> 4, tj = tid & 15;
    float lsum = 0.f;
    for (int jt = 0; jt < 64; ++jt) {
        __syncthreads();
        float4 w = *(const float4*)&z2g[((size_t)b * NSP + jt * 16 + lrow) * OUTD + lc4 * 4];
        *(float4*)&z2s[lrow * 68 + lc4 * 4] = w;
        __syncthreads();
        float dot = 0.f;
        #pragma unroll
        for (int k4 = 0; k4 < 16; ++k4) {
            float4 a = *(const float4*)&z1s[ti * 68 + k4 * 4];
            float4 bb = *(const float4*)&z2s[tj * 68 + k4 * 4];
            dot += a.x * bb.x + a.y * bb.y + a.z * bb.z + a.w * bb.w;
        }
        float sim = dot * 10.0f;           // 1/TEMPERATURE
        lsum += expf(sim);
        if (jt * 16 + tj == i0 + ti) diag[ti] = sim;
    }
    reds[ti * 17 + tj] = lsum;
    __syncthreads();
    if (tid < 16) {
        float tot = 0.f;
        for (int t = 0; t < 16; ++t) tot += reds[tid * 17 + t];
        row_loss[b * NSP + i0 + tid] = -diag[tid] + logf(tot);
    }
}

// ---------------- final mean over 4096 rows ------------------------------------
__global__ __launch_bounds__(256) void reduce_kernel(const float* __restrict__ row_loss,
                                                     float* __restrict__ out) {
    int tid = threadIdx.x;
    float s = 0.f;
    for (int i = tid; i < NB * NSP; i += 256) s += row_loss[i];
    for (int off = 32; off > 0; off >>= 1) s += __shfl_down(s, off, 64);
    __shared__ float wsum[4];
    if ((tid & 63) == 0) wsum[tid >> 6] = s;
    __syncthreads();
    if (tid == 0) out[0] = (wsum[0] + wsum[1] + wsum[2] + wsum[3]) * (1.0f / (NB * NSP));
}

extern "C" void kernel_launch(void* const* d_in, const int* in_sizes, int n_in,
                              void* d_out, int out_size, void* d_ws, size_t ws_size,
                              hipStream_t stream) {
    const float* feat = (const float*)d_in[0];
    const int* idx = (const int*)d_in[1];
    const float* W1 = (const float*)d_in[2];
    const float* b1 = (const float*)d_in[3];
    const float* W2 = (const float*)d_in[4];
    const float* b2 = (const float*)d_in[5];
    const float* Wp1 = (const float*)d_in[6];
    const float* bp1 = (const float*)d_in[7];
    const float* Wp2 = (const float*)d_in[8];
    const float* bp2 = (const float*)d_in[9];

    float* ws = (float*)d_ws;
    size_t off = 0;
    float* sp_sum   = ws + off; off += (size_t)NB * NSP * NC;      // 1,048,576
    float* adj      = ws + off; off += (size_t)NB * NSP * NSP;     // 4,194,304
    float* deg_inv  = ws + off; off += (size_t)NB * NSP;
    float* x        = ws + off; off += (size_t)NB * NSP * NC;
    float* z1g      = ws + off; off += (size_t)NB * NSP * OUTD;
    float* z2g      = ws + off; off += (size_t)NB * NSP * OUTD;
    float* row_loss = ws + off; off += (size_t)NB * NSP;
    unsigned* counts_u = (unsigned*)(ws + off); off += (size_t)NB * NSP;
    unsigned* offsets  = (unsigned*)(ws + off); off += (size_t)NB * (NSP + 1);
    unsigned* cursor   = (unsigned*)(ws + off); off += (size_t)NB * NSP;
    int* rank          = (int*)(ws + off);      off += (size_t)NB * NPIX;  // 262,144
    // align featP to 16B
    off = (off + 3) & ~(size_t)3;
    float* featP       = ws + off;              off += (size_t)NPIX * NC; // 16,777,216 (per-image reuse)
    // total ~ 95 MB

    hipMemsetAsync(adj, 0, (size_t)NB * NSP * NSP * sizeof(float), stream);
    hipMemsetAsync(counts_u, 0, (size_t)NB * NSP * sizeof(unsigned), stream);

    hist_kernel<<<dim3(64, NB), 256, 0, stream>>>(idx, counts_u);
    scan_kernel<<<NB, 256, 0, stream>>>(counts_u, offsets, cursor);
    rank_kernel<<<dim3(64, NB), 256, 0, stream>>>(idx, cursor, rank);

    int total_adj = NB * (2 * 65280 + NSP);
    adj_kernel<<<(total_adj + 255) / 256, 256, 0, stream>>>(idx, adj);
    deg_kernel<<<NB * NSP, 256, 0, stream>>>(adj, deg_inv);

    for (int b = 0; b < NB; ++b) {
        transpose_kernel<<<NPIX / 32, 256, 0, stream>>>(feat, rank, featP, b);
        segsum_kernel<<<NSP, 256, 0, stream>>>(featP, offsets, deg_inv, sp_sum, b);
    }

    conv_kernel<<<dim3(NC / 64, NSP / 64, NB), 256, 0, stream>>>(adj, sp_sum, deg_inv, x);
    encoder_kernel<<<NB * 64, 256, 0, stream>>>(x, W1, b1, W2, b2, Wp1, bp1, Wp2, bp2, z1g, z2g);
    infonce_kernel<<<NB * 64, 256, 0, stream>>>(z1g, z2g, row_loss);
    reduce_kernel<<<1, 256, 0, stream>>>(row_loss, (float*)d_out);
}

// Round 4
// 585.228 us; speedup vs baseline: 1.4107x; 1.1524x over previous
//
#include <hip/hip_runtime.h>
#include <math.h>

#define NB 4
#define NC 256
#define NPIX 65536
#define NSP 1024
#define OUTD 64

typedef short bfrag_t __attribute__((ext_vector_type(8)));
typedef float cfrag_t __attribute__((ext_vector_type(4)));

__device__ __forceinline__ unsigned short f2bf(float f) {
    union { float f; unsigned u; } v; v.f = f;
    unsigned r = (v.u + 0x7FFFu + ((v.u >> 16) & 1u)) >> 16;
    return (unsigned short)r;
}
__device__ __forceinline__ float bf2f(unsigned short h) {
    union { unsigned u; float f; } v; v.u = ((unsigned)h) << 16;
    return v.f;
}

// ---------------- hist: LDS histogram per 1024-pixel tile -> global merge -----
__global__ __launch_bounds__(256) void hist_kernel(const int* __restrict__ idx,
                                                   unsigned* __restrict__ counts_u) {
    __shared__ unsigned cnt[NSP];
    int b = blockIdx.y;
    int tid = threadIdx.x;
    for (int s = tid; s < NSP; s += 256) cnt[s] = 0u;
    __syncthreads();
    const int4* idx4 = (const int4*)(idx + b * NPIX + blockIdx.x * 1024);
    int4 s4 = idx4[tid];
    atomicAdd(&cnt[s4.x], 1u);
    atomicAdd(&cnt[s4.y], 1u);
    atomicAdd(&cnt[s4.z], 1u);
    atomicAdd(&cnt[s4.w], 1u);
    __syncthreads();
    for (int s = tid; s < NSP; s += 256)
        if (cnt[s]) atomicAdd(&counts_u[b * NSP + s], cnt[s]);
}

// ---------------- scan: exclusive prefix over 1024 bins per image --------------
__global__ __launch_bounds__(256) void scan_kernel(const unsigned* __restrict__ counts_u,
                                                   unsigned* __restrict__ offsets,
                                                   unsigned* __restrict__ cursor) {
    int b = blockIdx.x;
    int tid = threadIdx.x;
    __shared__ unsigned v[256];
    unsigned c0 = counts_u[b * NSP + tid * 4 + 0];
    unsigned c1 = counts_u[b * NSP + tid * 4 + 1];
    unsigned c2 = counts_u[b * NSP + tid * 4 + 2];
    unsigned c3 = counts_u[b * NSP + tid * 4 + 3];
    v[tid] = c0 + c1 + c2 + c3;
    __syncthreads();
    for (int off = 1; off < 256; off <<= 1) {
        unsigned t = (tid >= off) ? v[tid - off] : 0u;
        __syncthreads();
        v[tid] += t;
        __syncthreads();
    }
    unsigned base = tid ? v[tid - 1] : 0u;
    unsigned o0 = base, o1 = base + c0, o2 = base + c0 + c1, o3 = base + c0 + c1 + c2;
    offsets[b * (NSP + 1) + tid * 4 + 0] = o0;
    offsets[b * (NSP + 1) + tid * 4 + 1] = o1;
    offsets[b * (NSP + 1) + tid * 4 + 2] = o2;
    offsets[b * (NSP + 1) + tid * 4 + 3] = o3;
    cursor[b * NSP + tid * 4 + 0] = o0;
    cursor[b * NSP + tid * 4 + 1] = o1;
    cursor[b * NSP + tid * 4 + 2] = o2;
    cursor[b * NSP + tid * 4 + 3] = o3;
    if (tid == 255) offsets[b * (NSP + 1) + NSP] = v[255];
}

// ---------------- rank: sorted position of each pixel (two-level atomics) ------
__global__ __launch_bounds__(256) void rank_kernel(const int* __restrict__ idx,
                                                   unsigned* __restrict__ cursor,
                                                   int* __restrict__ rank) {
    __shared__ unsigned lcnt[NSP];
    __shared__ unsigned base[NSP];
    int b = blockIdx.y;
    int tid = threadIdx.x;
    for (int s = tid; s < NSP; s += 256) lcnt[s] = 0u;
    __syncthreads();
    const int4* idx4 = (const int4*)(idx + b * NPIX + blockIdx.x * 1024);
    int4 s4 = idx4[tid];
    unsigned r0 = atomicAdd(&lcnt[s4.x], 1u);
    unsigned r1 = atomicAdd(&lcnt[s4.y], 1u);
    unsigned r2 = atomicAdd(&lcnt[s4.z], 1u);
    unsigned r3 = atomicAdd(&lcnt[s4.w], 1u);
    __syncthreads();
    for (int s = tid; s < NSP; s += 256) {
        unsigned c = lcnt[s];
        base[s] = c ? atomicAdd(&cursor[b * NSP + s], c) : 0u;
    }
    __syncthreads();
    int p = b * NPIX + blockIdx.x * 1024 + tid * 4;
    rank[p + 0] = (int)(base[s4.x] + r0);
    rank[p + 1] = (int)(base[s4.y] + r1);
    rank[p + 2] = (int)(base[s4.z] + r2);
    rank[p + 3] = (int)(base[s4.w] + r3);
}

// ---------------- transpose+permute: feat[C][HW] -> featP[rank[p]][C] bf16 -----
__global__ __launch_bounds__(256) void transpose_kernel(const float* __restrict__ feat,
                                                        const int* __restrict__ rank,
                                                        unsigned short* __restrict__ featP) {
    __shared__ unsigned short tile[64 * 260];
    __shared__ int rk[64];
    int b = blockIdx.y;
    int p0 = blockIdx.x * 64;
    int tid = threadIdx.x;
    if (tid < 64) rk[tid] = rank[b * NPIX + p0 + tid];
    int cg = tid >> 4;          // channel-in-pass 0..15
    int x4 = tid & 15;          // float4 group -> pixels x4*4..+3
    #pragma unroll
    for (int pass = 0; pass < 16; ++pass) {
        int c = pass * 16 + cg;
        float4 v = *(const float4*)&feat[((size_t)(b * NC + c)) * NPIX + p0 + x4 * 4];
        tile[(x4 * 4 + 0) * 260 + c] = f2bf(v.x);
        tile[(x4 * 4 + 1) * 260 + c] = f2bf(v.y);
        tile[(x4 * 4 + 2) * 260 + c] = f2bf(v.z);
        tile[(x4 * 4 + 3) * 260 + c] = f2bf(v.w);
    }
    __syncthreads();
    int c4 = tid & 63;
    int r0 = tid >> 6;
    #pragma unroll
    for (int pass = 0; pass < 16; ++pass) {
        int row = pass * 4 + r0;
        ushort4 w = *(const ushort4*)&tile[row * 260 + c4 * 4];
        *(ushort4*)&featP[((size_t)b * NPIX + rk[row]) * NC + c4 * 4] = w;
    }
}

// ---------------- segmented sum (bf16 in, fp32 acc) + mean + deg_inv fold ------
__global__ __launch_bounds__(256) void segsum_kernel(const unsigned short* __restrict__ featP,
                                                     const unsigned* __restrict__ offsets,
                                                     const float* __restrict__ deg_inv,
                                                     float* __restrict__ spf) {
    int b = blockIdx.y, s = blockIdx.x, c = threadIdx.x;
    unsigned j0 = offsets[b * (NSP + 1) + s];
    unsigned j1 = offsets[b * (NSP + 1) + s + 1];
    const unsigned short* base = featP + (size_t)b * NPIX * NC + c;
    float a0 = 0.f, a1 = 0.f, a2 = 0.f, a3 = 0.f;
    unsigned j = j0;
    for (; j + 4 <= j1; j += 4) {
        a0 += bf2f(base[(size_t)(j + 0) * NC]);
        a1 += bf2f(base[(size_t)(j + 1) * NC]);
        a2 += bf2f(base[(size_t)(j + 2) * NC]);
        a3 += bf2f(base[(size_t)(j + 3) * NC]);
    }
    for (; j < j1; ++j) a0 += bf2f(base[(size_t)j * NC]);
    float acc = (a0 + a1) + (a2 + a3);
    unsigned cnt = j1 - j0;
    float scale = cnt ? deg_inv[b * NSP + s] / (float)cnt : 0.f;
    spf[((size_t)b * NSP + s) * NC + c] = acc * scale;
}

// ---------------- spfT[c][s] bf16 <- spf[s][c] fp32 (B^T for MFMA) -------------
__global__ __launch_bounds__(256) void spft_kernel(const float* __restrict__ spf,
                                                   unsigned short* __restrict__ spfT) {
    __shared__ unsigned short t[64 * 68];
    int b = blockIdx.z;
    int s0 = blockIdx.x * 64, c0 = blockIdx.y * 64;
    int tid = threadIdx.x;
    int sl = tid >> 4, c4 = tid & 15;
    #pragma unroll
    for (int it = 0; it < 4; ++it) {
        int s = it * 16 + sl;
        float4 v = *(const float4*)&spf[((size_t)b * NSP + s0 + s) * NC + c0 + c4 * 4];
        t[(c4 * 4 + 0) * 68 + s] = f2bf(v.x);
        t[(c4 * 4 + 1) * 68 + s] = f2bf(v.y);
        t[(c4 * 4 + 2) * 68 + s] = f2bf(v.z);
        t[(c4 * 4 + 3) * 68 + s] = f2bf(v.w);
    }
    __syncthreads();
    int cl = tid >> 4, s4 = tid & 15;
    #pragma unroll
    for (int it = 0; it < 4; ++it) {
        int c = it * 16 + cl;
        ushort4 w = *(const ushort4*)&t[c * 68 + s4 * 4];
        *(ushort4*)&spfT[((size_t)b * NC + c0 + c) * NSP + s0 + s4 * 4] = w;
    }
}

// ---------------- binary adjacency in bf16 (idempotent 1.0 stores) + eye -------
__global__ __launch_bounds__(256) void adj_kernel(const int* __restrict__ idx,
                                                  unsigned short* __restrict__ adj) {
    const int PAIRS = 65280;
    const int PERB = 2 * PAIRS + NSP;
    int i = blockIdx.x * 256 + threadIdx.x;
    if (i >= NB * PERB) return;
    int b = i / PERB;
    int r = i % PERB;
    unsigned short* A = adj + (size_t)b * NSP * NSP;
    const int* id = idx + b * NPIX;
    if (r >= 2 * PAIRS) {
        int s = r - 2 * PAIRS;
        A[s * NSP + s] = 0x3F80;          // 1.0 bf16
        return;
    }
    int p1, p2;
    if (r < PAIRS) {
        int row = r / 255, col = r % 255;
        p1 = row * 256 + col; p2 = p1 + 1;
    } else {
        int rv = r - PAIRS;
        p1 = rv; p2 = rv + 256;
    }
    int s1 = id[p1], s2 = id[p2];
    if (s1 != s2) {
        A[s1 * NSP + s2] = 0x3F80;
        A[s2 * NSP + s1] = 0x3F80;
    }
}

// ---------------- deg_inv[row] = 1/sqrt(#nonzero in bf16 row) ------------------
__global__ __launch_bounds__(256) void deg_kernel(const unsigned short* __restrict__ adj,
                                                  float* __restrict__ deg_inv) {
    int row = blockIdx.x;                 // 0 .. NB*NSP-1
    int tid = threadIdx.x;
    const unsigned* a2 = (const unsigned*)(adj + (size_t)row * NSP);
    unsigned u0 = a2[tid], u1 = a2[tid + 256];
    float s = (float)((u0 & 0xFFFFu) != 0) + (float)((u0 >> 16) != 0)
            + (float)((u1 & 0xFFFFu) != 0) + (float)((u1 >> 16) != 0);
    for (int off = 32; off > 0; off >>= 1) s += __shfl_down(s, off, 64);
    __shared__ float wsum[4];
    if ((tid & 63) == 0) wsum[tid >> 6] = s;
    __syncthreads();
    if (tid == 0) deg_inv[row] = 1.0f / sqrtf(wsum[0] + wsum[1] + wsum[2] + wsum[3]);
}

// ---------------- x = deg_i * (A_bin @ spf_scaled) via bf16 MFMA ---------------
__global__ __launch_bounds__(256) void conv_kernel(const unsigned short* __restrict__ adjb,
                                                   const unsigned short* __restrict__ spfT,
                                                   const float* __restrict__ deg_inv,
                                                   float* __restrict__ x) {
    __shared__ __align__(16) unsigned short Al[64 * 72];
    __shared__ __align__(16) unsigned short Bl[64 * 72];
    int b = blockIdx.z;
    int i0 = blockIdx.y * 64, c0 = blockIdx.x * 64;
    int tid = threadIdx.x;
    int wave = tid >> 6, lane = tid & 63;
    int wm = wave >> 1, wn = wave & 1;
    const unsigned short* A = adjb + (size_t)b * NSP * NSP;
    const unsigned short* Bt = spfT + (size_t)b * NC * NSP;
    cfrag_t acc[2][2] = {{{0.f, 0.f, 0.f, 0.f}, {0.f, 0.f, 0.f, 0.f}},
                         {{0.f, 0.f, 0.f, 0.f}, {0.f, 0.f, 0.f, 0.f}}};
    // staging: full 64x64 tile = 64 rows x 8 x 16B chunks; 256 threads do
    // rows 0..31 and 32..63 in two statements (FIX of R3's half-staged tile)
    int sr2 = tid >> 3, sc2 = tid & 7;
    int q = lane >> 4, m = lane & 15;
    for (int kt = 0; kt < 16; ++kt) {
        int k0 = kt * 64;
        __syncthreads();
        *(uint4*)&Al[sr2 * 72 + sc2 * 8] =
            *(const uint4*)&A[(size_t)(i0 + sr2) * NSP + k0 + sc2 * 8];
        *(uint4*)&Al[(sr2 + 32) * 72 + sc2 * 8] =
            *(const uint4*)&A[(size_t)(i0 + sr2 + 32) * NSP + k0 + sc2 * 8];
        *(uint4*)&Bl[sr2 * 72 + sc2 * 8] =
            *(const uint4*)&Bt[(size_t)(c0 + sr2) * NSP + k0 + sc2 * 8];
        *(uint4*)&Bl[(sr2 + 32) * 72 + sc2 * 8] =
            *(const uint4*)&Bt[(size_t)(c0 + sr2 + 32) * NSP + k0 + sc2 * 8];
        __syncthreads();
        #pragma unroll
        for (int ks = 0; ks < 2; ++ks) {
            int kk = ks * 32 + q * 8;
            bfrag_t a0 = *(const bfrag_t*)&Al[(wm * 32 + m) * 72 + kk];
            bfrag_t a1 = *(const bfrag_t*)&Al[(wm * 32 + 16 + m) * 72 + kk];
            bfrag_t b0 = *(const bfrag_t*)&Bl[(wn * 32 + m) * 72 + kk];
            bfrag_t b1 = *(const bfrag_t*)&Bl[(wn * 32 + 16 + m) * 72 + kk];
            acc[0][0] = __builtin_amdgcn_mfma_f32_16x16x32_bf16(a0, b0, acc[0][0], 0, 0, 0);
            acc[0][1] = __builtin_amdgcn_mfma_f32_16x16x32_bf16(a0, b1, acc[0][1], 0, 0, 0);
            acc[1][0] = __builtin_amdgcn_mfma_f32_16x16x32_bf16(a1, b0, acc[1][0], 0, 0, 0);
            acc[1][1] = __builtin_amdgcn_mfma_f32_16x16x32_bf16(a1, b1, acc[1][1], 0, 0, 0);
        }
    }
    int col = lane & 15, rbase = (lane >> 4) * 4;
    #pragma unroll
    for (int mi = 0; mi < 2; ++mi) {
        #pragma unroll
        for (int reg = 0; reg < 4; ++reg) {
            int gi = i0 + wm * 32 + mi * 16 + rbase + reg;
            float di = deg_inv[b * NSP + gi];
            #pragma unroll
            for (int ni = 0; ni < 2; ++ni) {
                int gc = c0 + wn * 32 + ni * 16 + col;
                x[((size_t)b * NSP + gi) * NC + gc] = acc[mi][ni][reg] * di;
            }
        }
    }
}

// ---------------- fused encoder: x -> h1 -> h2 -> z1,z2 (row-normalized) -------
__global__ __launch_bounds__(256) void encoder_kernel(
    const float* __restrict__ x,
    const float* __restrict__ W1, const float* __restrict__ b1,
    const float* __restrict__ W2, const float* __restrict__ b2,
    const float* __restrict__ Wp1, const float* __restrict__ bp1,
    const float* __restrict__ Wp2, const float* __restrict__ bp2,
    float* __restrict__ z1g, float* __restrict__ z2g) {
    __shared__ float xs[16 * 260];
    __shared__ float h1s[16 * 132];
    __shared__ float h2s[16 * 132];
    __shared__ float red1[16 * 17], red2[16 * 17];
    __shared__ float inv1[16], inv2[16];
    int blk = blockIdx.x;
    int b = blk >> 6;
    int r0 = (blk & 63) * 16;
    int tid = threadIdx.x;
    for (int it = 0; it < 4; ++it) {
        int fl = it * 256 + tid;
        int row = fl >> 6, c4 = fl & 63;
        float4 v = *(const float4*)&x[((size_t)b * NSP + r0 + row) * NC + c4 * 4];
        *(float4*)&xs[row * 260 + c4 * 4] = v;
    }
    __syncthreads();
    int r = tid & 15, tc = tid >> 4;
    float acc[8] = {};
    for (int k4 = 0; k4 < 64; ++k4) {
        float4 xv = *(const float4*)&xs[r * 260 + k4 * 4];
        #pragma unroll
        for (int u = 0; u < 8; ++u) {
            int n = tc * 8 + u;
            float4 wv = *(const float4*)&W1[n * 256 + k4 * 4];
            acc[u] += xv.x * wv.x + xv.y * wv.y + xv.z * wv.z + xv.w * wv.w;
        }
    }
    #pragma unroll
    for (int u = 0; u < 8; ++u) {
        int n = tc * 8 + u;
        h1s[r * 132 + n] = fmaxf(acc[u] + b1[n], 0.f);
    }
    __syncthreads();
    float acc2[8] = {};
    for (int k4 = 0; k4 < 32; ++k4) {
        float4 hv = *(const float4*)&h1s[r * 132 + k4 * 4];
        #pragma unroll
        for (int u = 0; u < 8; ++u) {
            int n = tc * 8 + u;
            float4 wv = *(const float4*)&W2[n * 128 + k4 * 4];
            acc2[u] += hv.x * wv.x + hv.y * wv.y + hv.z * wv.z + hv.w * wv.w;
        }
    }
    #pragma unroll
    for (int u = 0; u < 8; ++u) {
        int n = tc * 8 + u;
        h2s[r * 132 + n] = fmaxf(acc2[u] + b2[n], 0.f);
    }
    __syncthreads();
    float az1[4] = {}, az2[4] = {};
    for (int k4 = 0; k4 < 32; ++k4) {
        float4 hv = *(const float4*)&h2s[r * 132 + k4 * 4];
        #pragma unroll
        for (int u = 0; u < 4; ++u) {
            int n = tc * 4 + u;
            float4 w1v = *(const float4*)&Wp1[n * 128 + k4 * 4];
            float4 w2v = *(const float4*)&Wp2[n * 128 + k4 * 4];
            az1[u] += hv.x * w1v.x + hv.y * w1v.y + hv.z * w1v.z + hv.w * w1v.w;
            az2[u] += hv.x * w2v.x + hv.y * w2v.y + hv.z * w2v.z + hv.w * w2v.w;
        }
    }
    float ss1 = 0.f, ss2 = 0.f;
    #pragma unroll
    for (int u = 0; u < 4; ++u) {
        int n = tc * 4 + u;
        az1[u] += bp1[n]; az2[u] += bp2[n];
        ss1 += az1[u] * az1[u];
        ss2 += az2[u] * az2[u];
    }
    red1[r * 17 + tc] = ss1;
    red2[r * 17 + tc] = ss2;
    __syncthreads();
    if (tid < 16) {
        float s1 = 0.f, s2 = 0.f;
        for (int t = 0; t < 16; ++t) { s1 += red1[tid * 17 + t]; s2 += red2[tid * 17 + t]; }
        inv1[tid] = 1.0f / sqrtf(s1);
        inv2[tid] = 1.0f / sqrtf(s2);
    }
    __syncthreads();
    float i1 = inv1[r], i2 = inv2[r];
    float4 o1 = {az1[0] * i1, az1[1] * i1, az1[2] * i1, az1[3] * i1};
    float4 o2 = {az2[0] * i2, az2[1] * i2, az2[2] * i2, az2[3] * i2};
    *(float4*)&z1g[((size_t)b * NSP + r0 + r) * OUTD + tc * 4] = o1;
    *(float4*)&z2g[((size_t)b * NSP + r0 + r) * OUTD + tc * 4] = o2;
}

// ---------------- InfoNCE rows: loss_i = -sim_ii + log(sum_j exp(sim_ij)) ------
__global__ __launch_bounds__(256) void infonce_kernel(const float* __restrict__ z1g,
                                                      const float* __restrict__ z2g,
                                                      float* __restrict__ row_loss) {
    __shared__ float z1s[16 * 68];
    __shared__ float z2s[16 * 68];
    __shared__ float reds[16 * 17];
    __shared__ float diag[16];
    int blk = blockIdx.x;
    int b = blk >> 6;
    int i0 = (blk & 63) * 16;
    int tid = threadIdx.x;
    int lrow = tid >> 4, lc4 = tid & 15;
    float4 v = *(const float4*)&z1g[((size_t)b * NSP + i0 + lrow) * OUTD + lc4 * 4];
    *(float4*)&z1s[lrow * 68 + lc4 * 4] = v;
    int ti = tid >> 4, tj = tid & 15;
    float lsum = 0.f;
    for (int jt = 0; jt < 64; ++jt) {
        __syncthreads();
        float4 w = *(const float4*)&z2g[((size_t)b * NSP + jt * 16 + lrow) * OUTD + lc4 * 4];
        *(float4*)&z2s[lrow * 68 + lc4 * 4] = w;
        __syncthreads();
        float dot = 0.f;
        #pragma unroll
        for (int k4 = 0; k4 < 16; ++k4) {
            float4 a = *(const float4*)&z1s[ti * 68 + k4 * 4];
            float4 bb = *(const float4*)&z2s[tj * 68 + k4 * 4];
            dot += a.x * bb.x + a.y * bb.y + a.z * bb.z + a.w * bb.w;
        }
        float sim = dot * 10.0f;
        lsum += expf(sim);
        if (jt * 16 + tj == i0 + ti) diag[ti] = sim;
    }
    reds[ti * 17 + tj] = lsum;
    __syncthreads();
    if (tid < 16) {
        float tot = 0.f;
        for (int t = 0; t < 16; ++t) tot += reds[tid * 17 + t];
        row_loss[b * NSP + i0 + tid] = -diag[tid] + logf(tot);
    }
}

// ---------------- final mean over 4096 rows ------------------------------------
__global__ __launch_bounds__(256) void reduce_kernel(const float* __restrict__ row_loss,
                                                     float* __restrict__ out) {
    int tid = threadIdx.x;
    float s = 0.f;
    for (int i = tid; i < NB * NSP; i += 256) s += row_loss[i];
    for (int off = 32; off > 0; off >>= 1) s += __shfl_down(s, off, 64);
    __shared__ float wsum[4];
    if ((tid & 63) == 0) wsum[tid >> 6] = s;
    __syncthreads();
    if (tid == 0) out[0] = (wsum[0] + wsum[1] + wsum[2] + wsum[3]) * (1.0f / (NB * NSP));
}

extern "C" void kernel_launch(void* const* d_in, const int* in_sizes, int n_in,
                              void* d_out, int out_size, void* d_ws, size_t ws_size,
                              hipStream_t stream) {
    const float* feat = (const float*)d_in[0];
    const int* idx = (const int*)d_in[1];
    const float* W1 = (const float*)d_in[2];
    const float* b1 = (const float*)d_in[3];
    const float* W2 = (const float*)d_in[4];
    const float* b2 = (const float*)d_in[5];
    const float* Wp1 = (const float*)d_in[6];
    const float* bp1 = (const float*)d_in[7];
    const float* Wp2 = (const float*)d_in[8];
    const float* bp2 = (const float*)d_in[9];

    char* wsb = (char*)d_ws;
    size_t off = 0;
    auto alloc = [&](size_t bytes) -> void* {
        void* p = wsb + off;
        off += (bytes + 255) & ~(size_t)255;
        return p;
    };
    unsigned short* adjb  = (unsigned short*)alloc((size_t)NB * NSP * NSP * 2);   // 8 MB
    float* deg_inv        = (float*)alloc((size_t)NB * NSP * 4);
    float* spf            = (float*)alloc((size_t)NB * NSP * NC * 4);             // 4 MB
    unsigned short* spfT  = (unsigned short*)alloc((size_t)NB * NC * NSP * 2);    // 2 MB
    float* x              = (float*)alloc((size_t)NB * NSP * NC * 4);             // 4 MB
    float* z1g            = (float*)alloc((size_t)NB * NSP * OUTD * 4);
    float* z2g            = (float*)alloc((size_t)NB * NSP * OUTD * 4);
    float* row_loss       = (float*)alloc((size_t)NB * NSP * 4);
    unsigned* counts_u    = (unsigned*)alloc((size_t)NB * NSP * 4);
    unsigned* offsets     = (unsigned*)alloc((size_t)NB * (NSP + 1) * 4);
    unsigned* cursor      = (unsigned*)alloc((size_t)NB * NSP * 4);
    int* rank             = (int*)alloc((size_t)NB * NPIX * 4);                   // 1 MB
    unsigned short* featP = (unsigned short*)alloc((size_t)NB * NPIX * NC * 2);   // 134 MB

    hipMemsetAsync(adjb, 0, (size_t)NB * NSP * NSP * 2, stream);
    hipMemsetAsync(counts_u, 0, (size_t)NB * NSP * 4, stream);

    hist_kernel<<<dim3(64, NB), 256, 0, stream>>>(idx, counts_u);
    scan_kernel<<<NB, 256, 0, stream>>>(counts_u, offsets, cursor);
    rank_kernel<<<dim3(64, NB), 256, 0, stream>>>(idx, cursor, rank);

    int total_adj = NB * (2 * 65280 + NSP);
    adj_kernel<<<(total_adj + 255) / 256, 256, 0, stream>>>(idx, adjb);
    deg_kernel<<<NB * NSP, 256, 0, stream>>>(adjb, deg_inv);

    transpose_kernel<<<dim3(NPIX / 64, NB), 256, 0, stream>>>(feat, rank, featP);
    segsum_kernel<<<dim3(NSP, NB), 256, 0, stream>>>(featP, offsets, deg_inv, spf);
    spft_kernel<<<dim3(NSP / 64, NC / 64, NB), 256, 0, stream>>>(spf, spfT);

    conv_kernel<<<dim3(NC / 64, NSP / 64, NB), 256, 0, stream>>>(adjb, spfT, deg_inv, x);
    encoder_kernel<<<NB * 64, 256, 0, stream>>>(x, W1, b1, W2, b2, Wp1, bp1, Wp2, bp2, z1g, z2g);
    infonce_kernel<<<NB * 64, 256, 0, stream>>>(z1g, z2g, row_loss);
    reduce_kernel<<<1, 256, 0, stream>>>(row_loss, (float*)d_out);
}

// Round 5
// 559.959 us; speedup vs baseline: 1.4743x; 1.0451x over previous
//
#include <hip/hip_runtime.h>
#include <math.h>

#define NB 4
#define NC 256
#define NPIX 65536
#define NSP 1024
#define OUTD 64

typedef short bfrag_t __attribute__((ext_vector_type(8)));
typedef float cfrag_t __attribute__((ext_vector_type(4)));
typedef float f32x2 __attribute__((ext_vector_type(2)));

__device__ __forceinline__ unsigned short f2bf(float f) {
    union { float f; unsigned u; } v; v.f = f;
    unsigned r = (v.u + 0x7FFFu + ((v.u >> 16) & 1u)) >> 16;
    return (unsigned short)r;
}
__device__ __forceinline__ float bf2f(unsigned short h) {
    union { unsigned u; float f; } v; v.u = ((unsigned)h) << 16;
    return v.f;
}

// ---------------- hist: LDS histogram per 1024-pixel tile -> global merge -----
__global__ __launch_bounds__(256) void hist_kernel(const int* __restrict__ idx,
                                                   unsigned* __restrict__ counts_u) {
    __shared__ unsigned cnt[NSP];
    int b = blockIdx.y;
    int tid = threadIdx.x;
    for (int s = tid; s < NSP; s += 256) cnt[s] = 0u;
    __syncthreads();
    const int4* idx4 = (const int4*)(idx + b * NPIX + blockIdx.x * 1024);
    int4 s4 = idx4[tid];
    atomicAdd(&cnt[s4.x], 1u);
    atomicAdd(&cnt[s4.y], 1u);
    atomicAdd(&cnt[s4.z], 1u);
    atomicAdd(&cnt[s4.w], 1u);
    __syncthreads();
    for (int s = tid; s < NSP; s += 256)
        if (cnt[s]) atomicAdd(&counts_u[b * NSP + s], cnt[s]);
}

// ---------------- scan: exclusive prefix over 1024 bins per image --------------
__global__ __launch_bounds__(256) void scan_kernel(const unsigned* __restrict__ counts_u,
                                                   unsigned* __restrict__ offsets,
                                                   unsigned* __restrict__ cursor) {
    int b = blockIdx.x;
    int tid = threadIdx.x;
    __shared__ unsigned v[256];
    unsigned c0 = counts_u[b * NSP + tid * 4 + 0];
    unsigned c1 = counts_u[b * NSP + tid * 4 + 1];
    unsigned c2 = counts_u[b * NSP + tid * 4 + 2];
    unsigned c3 = counts_u[b * NSP + tid * 4 + 3];
    v[tid] = c0 + c1 + c2 + c3;
    __syncthreads();
    for (int off = 1; off < 256; off <<= 1) {
        unsigned t = (tid >= off) ? v[tid - off] : 0u;
        __syncthreads();
        v[tid] += t;
        __syncthreads();
    }
    unsigned base = tid ? v[tid - 1] : 0u;
    unsigned o0 = base, o1 = base + c0, o2 = base + c0 + c1, o3 = base + c0 + c1 + c2;
    offsets[b * (NSP + 1) + tid * 4 + 0] = o0;
    offsets[b * (NSP + 1) + tid * 4 + 1] = o1;
    offsets[b * (NSP + 1) + tid * 4 + 2] = o2;
    offsets[b * (NSP + 1) + tid * 4 + 3] = o3;
    cursor[b * NSP + tid * 4 + 0] = o0;
    cursor[b * NSP + tid * 4 + 1] = o1;
    cursor[b * NSP + tid * 4 + 2] = o2;
    cursor[b * NSP + tid * 4 + 3] = o3;
    if (tid == 255) offsets[b * (NSP + 1) + NSP] = v[255];
}

// ---------------- rank: sorted position of each pixel (two-level atomics) ------
__global__ __launch_bounds__(256) void rank_kernel(const int* __restrict__ idx,
                                                   unsigned* __restrict__ cursor,
                                                   int* __restrict__ rank) {
    __shared__ unsigned lcnt[NSP];
    __shared__ unsigned base[NSP];
    int b = blockIdx.y;
    int tid = threadIdx.x;
    for (int s = tid; s < NSP; s += 256) lcnt[s] = 0u;
    __syncthreads();
    const int4* idx4 = (const int4*)(idx + b * NPIX + blockIdx.x * 1024);
    int4 s4 = idx4[tid];
    unsigned r0 = atomicAdd(&lcnt[s4.x], 1u);
    unsigned r1 = atomicAdd(&lcnt[s4.y], 1u);
    unsigned r2 = atomicAdd(&lcnt[s4.z], 1u);
    unsigned r3 = atomicAdd(&lcnt[s4.w], 1u);
    __syncthreads();
    for (int s = tid; s < NSP; s += 256) {
        unsigned c = lcnt[s];
        base[s] = c ? atomicAdd(&cursor[b * NSP + s], c) : 0u;
    }
    __syncthreads();
    int p = b * NPIX + blockIdx.x * 1024 + tid * 4;
    rank[p + 0] = (int)(base[s4.x] + r0);
    rank[p + 1] = (int)(base[s4.y] + r1);
    rank[p + 2] = (int)(base[s4.z] + r2);
    rank[p + 3] = (int)(base[s4.w] + r3);
}

// ------- transpose+permute: feat[C][HW] fp32 -> featP[rank[p]][C] fp8 e4m3 -----
__global__ __launch_bounds__(256) void transpose_kernel(const float* __restrict__ feat,
                                                        const int* __restrict__ rank,
                                                        unsigned char* __restrict__ featP) {
    __shared__ unsigned short tile[64 * 260];
    __shared__ int rk[64];
    int b = blockIdx.y;
    int p0 = blockIdx.x * 64;
    int tid = threadIdx.x;
    if (tid < 64) rk[tid] = rank[b * NPIX + p0 + tid];
    int cg = tid >> 4;          // channel-in-pass 0..15
    int x4 = tid & 15;          // float4 group -> pixels x4*4..+3
    #pragma unroll
    for (int pass = 0; pass < 16; ++pass) {
        int c = pass * 16 + cg;
        float4 v = *(const float4*)&feat[((size_t)(b * NC + c)) * NPIX + p0 + x4 * 4];
        tile[(x4 * 4 + 0) * 260 + c] = f2bf(v.x);
        tile[(x4 * 4 + 1) * 260 + c] = f2bf(v.y);
        tile[(x4 * 4 + 2) * 260 + c] = f2bf(v.z);
        tile[(x4 * 4 + 3) * 260 + c] = f2bf(v.w);
    }
    __syncthreads();
    int c4 = tid & 63;          // 4-channel group
    int r0 = tid >> 6;
    #pragma unroll
    for (int pass = 0; pass < 16; ++pass) {
        int row = pass * 4 + r0;
        ushort4 w = *(const ushort4*)&tile[row * 260 + c4 * 4];
        float f0 = bf2f(w.x), f1 = bf2f(w.y), f2 = bf2f(w.z), f3 = bf2f(w.w);
        int lo = __builtin_amdgcn_cvt_pk_fp8_f32(f0, f1, 0, false);
        int pk = __builtin_amdgcn_cvt_pk_fp8_f32(f2, f3, lo, true);
        *(unsigned*)&featP[((size_t)b * NPIX + rk[row]) * NC + c4 * 4] = (unsigned)pk;
    }
}

// ------- segmented sum (fp8 in, fp32 acc): wave = full 256B row, 4-wave split --
__global__ __launch_bounds__(256) void segsum_kernel(const unsigned char* __restrict__ featP,
                                                     const unsigned* __restrict__ offsets,
                                                     const float* __restrict__ deg_inv,
                                                     float* __restrict__ spf) {
    __shared__ float red[4][256];
    int b = blockIdx.y, s = blockIdx.x;
    int tid = threadIdx.x;
    int w = tid >> 6, lane = tid & 63;
    unsigned j0 = offsets[b * (NSP + 1) + s];
    unsigned j1 = offsets[b * (NSP + 1) + s + 1];
    const unsigned* base = (const unsigned*)(featP + (size_t)b * NPIX * NC);
    float a0 = 0.f, a1 = 0.f, a2 = 0.f, a3 = 0.f;
    for (unsigned j = j0 + w; j < j1; j += 4) {
        unsigned u = base[(size_t)j * 64 + lane];
        f32x2 lo = __builtin_amdgcn_cvt_pk_f32_fp8(u, false);
        f32x2 hi = __builtin_amdgcn_cvt_pk_f32_fp8(u, true);
        a0 += lo.x; a1 += lo.y; a2 += hi.x; a3 += hi.y;
    }
    *(float4*)&red[w][lane * 4] = (float4){a0, a1, a2, a3};
    __syncthreads();
    int c = tid;
    float sum = red[0][c] + red[1][c] + red[2][c] + red[3][c];
    unsigned cnt = j1 - j0;
    float scale = cnt ? deg_inv[b * NSP + s] / (float)cnt : 0.f;
    spf[((size_t)b * NSP + s) * NC + c] = sum * scale;
}

// ---------------- spfT[c][s] bf16 <- spf[s][c] fp32 (B^T for MFMA) -------------
__global__ __launch_bounds__(256) void spft_kernel(const float* __restrict__ spf,
                                                   unsigned short* __restrict__ spfT) {
    __shared__ unsigned short t[64 * 68];
    int b = blockIdx.z;
    int s0 = blockIdx.x * 64, c0 = blockIdx.y * 64;
    int tid = threadIdx.x;
    int sl = tid >> 4, c4 = tid & 15;
    #pragma unroll
    for (int it = 0; it < 4; ++it) {
        int s = it * 16 + sl;
        float4 v = *(const float4*)&spf[((size_t)b * NSP + s0 + s) * NC + c0 + c4 * 4];
        t[(c4 * 4 + 0) * 68 + s] = f2bf(v.x);
        t[(c4 * 4 + 1) * 68 + s] = f2bf(v.y);
        t[(c4 * 4 + 2) * 68 + s] = f2bf(v.z);
        t[(c4 * 4 + 3) * 68 + s] = f2bf(v.w);
    }
    __syncthreads();
    int cl = tid >> 4, s4 = tid & 15;
    #pragma unroll
    for (int it = 0; it < 4; ++it) {
        int c = it * 16 + cl;
        ushort4 w = *(const ushort4*)&t[c * 68 + s4 * 4];
        *(ushort4*)&spfT[((size_t)b * NC + c0 + c) * NSP + s0 + s4 * 4] = w;
    }
}

// ---------------- binary adjacency in bf16 (idempotent 1.0 stores) + eye -------
__global__ __launch_bounds__(256) void adj_kernel(const int* __restrict__ idx,
                                                  unsigned short* __restrict__ adj) {
    const int PAIRS = 65280;
    const int PERB = 2 * PAIRS + NSP;
    int i = blockIdx.x * 256 + threadIdx.x;
    if (i >= NB * PERB) return;
    int b = i / PERB;
    int r = i % PERB;
    unsigned short* A = adj + (size_t)b * NSP * NSP;
    const int* id = idx + b * NPIX;
    if (r >= 2 * PAIRS) {
        int s = r - 2 * PAIRS;
        A[s * NSP + s] = 0x3F80;          // 1.0 bf16
        return;
    }
    int p1, p2;
    if (r < PAIRS) {
        int row = r / 255, col = r % 255;
        p1 = row * 256 + col; p2 = p1 + 1;
    } else {
        int rv = r - PAIRS;
        p1 = rv; p2 = rv + 256;
    }
    int s1 = id[p1], s2 = id[p2];
    if (s1 != s2) {
        A[s1 * NSP + s2] = 0x3F80;
        A[s2 * NSP + s1] = 0x3F80;
    }
}

// ---------------- deg_inv[row] = 1/sqrt(#nonzero in bf16 row) ------------------
__global__ __launch_bounds__(256) void deg_kernel(const unsigned short* __restrict__ adj,
                                                  float* __restrict__ deg_inv) {
    int row = blockIdx.x;                 // 0 .. NB*NSP-1
    int tid = threadIdx.x;
    const unsigned* a2 = (const unsigned*)(adj + (size_t)row * NSP);
    unsigned u0 = a2[tid], u1 = a2[tid + 256];
    float s = (float)((u0 & 0xFFFFu) != 0) + (float)((u0 >> 16) != 0)
            + (float)((u1 & 0xFFFFu) != 0) + (float)((u1 >> 16) != 0);
    for (int off = 32; off > 0; off >>= 1) s += __shfl_down(s, off, 64);
    __shared__ float wsum[4];
    if ((tid & 63) == 0) wsum[tid >> 6] = s;
    __syncthreads();
    if (tid == 0) deg_inv[row] = 1.0f / sqrtf(wsum[0] + wsum[1] + wsum[2] + wsum[3]);
}

// ---------------- x = deg_i * (A_bin @ spf_scaled) via bf16 MFMA ---------------
__global__ __launch_bounds__(256) void conv_kernel(const unsigned short* __restrict__ adjb,
                                                   const unsigned short* __restrict__ spfT,
                                                   const float* __restrict__ deg_inv,
                                                   float* __restrict__ x) {
    __shared__ __align__(16) unsigned short Al[64 * 72];
    __shared__ __align__(16) unsigned short Bl[64 * 72];
    int b = blockIdx.z;
    int i0 = blockIdx.y * 64, c0 = blockIdx.x * 64;
    int tid = threadIdx.x;
    int wave = tid >> 6, lane = tid & 63;
    int wm = wave >> 1, wn = wave & 1;
    const unsigned short* A = adjb + (size_t)b * NSP * NSP;
    const unsigned short* Bt = spfT + (size_t)b * NC * NSP;
    cfrag_t acc[2][2] = {{{0.f, 0.f, 0.f, 0.f}, {0.f, 0.f, 0.f, 0.f}},
                         {{0.f, 0.f, 0.f, 0.f}, {0.f, 0.f, 0.f, 0.f}}};
    // full 64x64 K-tile staging: 64 rows x 8 x 16B chunks, 2 rows per thread
    int sr2 = tid >> 3, sc2 = tid & 7;
    int q = lane >> 4, m = lane & 15;
    for (int kt = 0; kt < 16; ++kt) {
        int k0 = kt * 64;
        __syncthreads();
        *(uint4*)&Al[sr2 * 72 + sc2 * 8] =
            *(const uint4*)&A[(size_t)(i0 + sr2) * NSP + k0 + sc2 * 8];
        *(uint4*)&Al[(sr2 + 32) * 72 + sc2 * 8] =
            *(const uint4*)&A[(size_t)(i0 + sr2 + 32) * NSP + k0 + sc2 * 8];
        *(uint4*)&Bl[sr2 * 72 + sc2 * 8] =
            *(const uint4*)&Bt[(size_t)(c0 + sr2) * NSP + k0 + sc2 * 8];
        *(uint4*)&Bl[(sr2 + 32) * 72 + sc2 * 8] =
            *(const uint4*)&Bt[(size_t)(c0 + sr2 + 32) * NSP + k0 + sc2 * 8];
        __syncthreads();
        #pragma unroll
        for (int ks = 0; ks < 2; ++ks) {
            int kk = ks * 32 + q * 8;
            bfrag_t a0 = *(const bfrag_t*)&Al[(wm * 32 + m) * 72 + kk];
            bfrag_t a1 = *(const bfrag_t*)&Al[(wm * 32 + 16 + m) * 72 + kk];
            bfrag_t b0 = *(const bfrag_t*)&Bl[(wn * 32 + m) * 72 + kk];
            bfrag_t b1 = *(const bfrag_t*)&Bl[(wn * 32 + 16 + m) * 72 + kk];
            acc[0][0] = __builtin_amdgcn_mfma_f32_16x16x32_bf16(a0, b0, acc[0][0], 0, 0, 0);
            acc[0][1] = __builtin_amdgcn_mfma_f32_16x16x32_bf16(a0, b1, acc[0][1], 0, 0, 0);
            acc[1][0] = __builtin_amdgcn_mfma_f32_16x16x32_bf16(a1, b0, acc[1][0], 0, 0, 0);
            acc[1][1] = __builtin_amdgcn_mfma_f32_16x16x32_bf16(a1, b1, acc[1][1], 0, 0, 0);
        }
    }
    int col = lane & 15, rbase = (lane >> 4) * 4;
    #pragma unroll
    for (int mi = 0; mi < 2; ++mi) {
        #pragma unroll
        for (int reg = 0; reg < 4; ++reg) {
            int gi = i0 + wm * 32 + mi * 16 + rbase + reg;
            float di = deg_inv[b * NSP + gi];
            #pragma unroll
            for (int ni = 0; ni < 2; ++ni) {
                int gc = c0 + wn * 32 + ni * 16 + col;
                x[((size_t)b * NSP + gi) * NC + gc] = acc[mi][ni][reg] * di;
            }
        }
    }
}

// ---------------- fused encoder: x -> h1 -> h2 -> z1,z2 (row-normalized) -------
__global__ __launch_bounds__(256) void encoder_kernel(
    const float* __restrict__ x,
    const float* __restrict__ W1, const float* __restrict__ b1,
    const float* __restrict__ W2, const float* __restrict__ b2,
    const float* __restrict__ Wp1, const float* __restrict__ bp1,
    const float* __restrict__ Wp2, const float* __restrict__ bp2,
    float* __restrict__ z1g, float* __restrict__ z2g) {
    __shared__ float xs[16 * 260];
    __shared__ float h1s[16 * 132];
    __shared__ float h2s[16 * 132];
    __shared__ float red1[16 * 17], red2[16 * 17];
    __shared__ float inv1[16], inv2[16];
    int blk = blockIdx.x;
    int b = blk >> 6;
    int r0 = (blk & 63) * 16;
    int tid = threadIdx.x;
    for (int it = 0; it < 4; ++it) {
        int fl = it * 256 + tid;
        int row = fl >> 6, c4 = fl & 63;
        float4 v = *(const float4*)&x[((size_t)b * NSP + r0 + row) * NC + c4 * 4];
        *(float4*)&xs[row * 260 + c4 * 4] = v;
    }
    __syncthreads();
    int r = tid & 15, tc = tid >> 4;
    float acc[8] = {};
    for (int k4 = 0; k4 < 64; ++k4) {
        float4 xv = *(const float4*)&xs[r * 260 + k4 * 4];
        #pragma unroll
        for (int u = 0; u < 8; ++u) {
            int n = tc * 8 + u;
            float4 wv = *(const float4*)&W1[n * 256 + k4 * 4];
            acc[u] += xv.x * wv.x + xv.y * wv.y + xv.z * wv.z + xv.w * wv.w;
        }
    }
    #pragma unroll
    for (int u = 0; u < 8; ++u) {
        int n = tc * 8 + u;
        h1s[r * 132 + n] = fmaxf(acc[u] + b1[n], 0.f);
    }
    __syncthreads();
    float acc2[8] = {};
    for (int k4 = 0; k4 < 32; ++k4) {
        float4 hv = *(const float4*)&h1s[r * 132 + k4 * 4];
        #pragma unroll
        for (int u = 0; u < 8; ++u) {
            int n = tc * 8 + u;
            float4 wv = *(const float4*)&W2[n * 128 + k4 * 4];
            acc2[u] += hv.x * wv.x + hv.y * wv.y + hv.z * wv.z + hv.w * wv.w;
        }
    }
    #pragma unroll
    for (int u = 0; u < 8; ++u) {
        int n = tc * 8 + u;
        h2s[r * 132 + n] = fmaxf(acc2[u] + b2[n], 0.f);
    }
    __syncthreads();
    float az1[4] = {}, az2[4] = {};
    for (int k4 = 0; k4 < 32; ++k4) {
        float4 hv = *(const float4*)&h2s[r * 132 + k4 * 4];
        #pragma unroll
        for (int u = 0; u < 4; ++u) {
            int n = tc * 4 + u;
            float4 w1v = *(const float4*)&Wp1[n * 128 + k4 * 4];
            float4 w2v = *(const float4*)&Wp2[n * 128 + k4 * 4];
            az1[u] += hv.x * w1v.x + hv.y * w1v.y + hv.z * w1v.z + hv.w * w1v.w;
            az2[u] += hv.x * w2v.x + hv.y * w2v.y + hv.z * w2v.z + hv.w * w2v.w;
        }
    }
    float ss1 = 0.f, ss2 = 0.f;
    #pragma unroll
    for (int u = 0; u < 4; ++u) {
        int n = tc * 4 + u;
        az1[u] += bp1[n]; az2[u] += bp2[n];
        ss1 += az1[u] * az1[u];
        ss2 += az2[u] * az2[u];
    }
    red1[r * 17 + tc] = ss1;
    red2[r * 17 + tc] = ss2;
    __syncthreads();
    if (tid < 16) {
        float s1 = 0.f, s2 = 0.f;
        for (int t = 0; t < 16; ++t) { s1 += red1[tid * 17 + t]; s2 += red2[tid * 17 + t]; }
        inv1[tid] = 1.0f / sqrtf(s1);
        inv2[tid] = 1.0f / sqrtf(s2);
    }
    __syncthreads();
    float i1 = inv1[r], i2 = inv2[r];
    float4 o1 = {az1[0] * i1, az1[1] * i1, az1[2] * i1, az1[3] * i1};
    float4 o2 = {az2[0] * i2, az2[1] * i2, az2[2] * i2, az2[3] * i2};
    *(float4*)&z1g[((size_t)b * NSP + r0 + r) * OUTD + tc * 4] = o1;
    *(float4*)&z2g[((size_t)b * NSP + r0 + r) * OUTD + tc * 4] = o2;
}

// ---------------- InfoNCE rows: loss_i = -sim_ii + log(sum_j exp(sim_ij)) ------
__global__ __launch_bounds__(256) void infonce_kernel(const float* __restrict__ z1g,
                                                      const float* __restrict__ z2g,
                                                      float* __restrict__ row_loss) {
    __shared__ float z1s[16 * 68];
    __shared__ float z2s[16 * 68];
    __shared__ float reds[16 * 17];
    __shared__ float diag[16];
    int blk = blockIdx.x;
    int b = blk >> 6;
    int i0 = (blk & 63) * 16;
    int tid = threadIdx.x;
    int lrow = tid >> 4, lc4 = tid & 15;
    float4 v = *(const float4*)&z1g[((size_t)b * NSP + i0 + lrow) * OUTD + lc4 * 4];
    // pre-scale z1 by 1/TEMPERATURE so sim = dot directly
    v.x *= 10.0f; v.y *= 10.0f; v.z *= 10.0f; v.w *= 10.0f;
    *(float4*)&z1s[lrow * 68 + lc4 * 4] = v;
    int ti = tid >> 4, tj = tid & 15;
    float lsum = 0.f;
    for (int jt = 0; jt < 64; ++jt) {
        __syncthreads();
        float4 w = *(const float4*)&z2g[((size_t)b * NSP + jt * 16 + lrow) * OUTD + lc4 * 4];
        *(float4*)&z2s[lrow * 68 + lc4 * 4] = w;
        __syncthreads();
        float dot = 0.f;
        #pragma unroll
        for (int k4 = 0; k4 < 16; ++k4) {
            float4 a = *(const float4*)&z1s[ti * 68 + k4 * 4];
            float4 bb = *(const float4*)&z2s[tj * 68 + k4 * 4];
            dot += a.x * bb.x + a.y * bb.y + a.z * bb.z + a.w * bb.w;
        }
        lsum += __expf(dot);
        if (jt * 16 + tj == i0 + ti) diag[ti] = dot;
    }
    reds[ti * 17 + tj] = lsum;
    __syncthreads();
    if (tid < 16) {
        float tot = 0.f;
        for (int t = 0; t < 16; ++t) tot += reds[tid * 17 + t];
        row_loss[b * NSP + i0 + tid] = -diag[tid] + __logf(tot);
    }
}

// ---------------- final mean over 4096 rows ------------------------------------
__global__ __launch_bounds__(256) void reduce_kernel(const float* __restrict__ row_loss,
                                                     float* __restrict__ out) {
    int tid = threadIdx.x;
    float s = 0.f;
    for (int i = tid; i < NB * NSP; i += 256) s += row_loss[i];
    for (int off = 32; off > 0; off >>= 1) s += __shfl_down(s, off, 64);
    __shared__ float wsum[4];
    if ((tid & 63) == 0) wsum[tid >> 6] = s;
    __syncthreads();
    if (tid == 0) out[0] = (wsum[0] + wsum[1] + wsum[2] + wsum[3]) * (1.0f / (NB * NSP));
}

extern "C" void kernel_launch(void* const* d_in, const int* in_sizes, int n_in,
                              void* d_out, int out_size, void* d_ws, size_t ws_size,
                              hipStream_t stream) {
    const float* feat = (const float*)d_in[0];
    const int* idx = (const int*)d_in[1];
    const float* W1 = (const float*)d_in[2];
    const float* b1 = (const float*)d_in[3];
    const float* W2 = (const float*)d_in[4];
    const float* b2 = (const float*)d_in[5];
    const float* Wp1 = (const float*)d_in[6];
    const float* bp1 = (const float*)d_in[7];
    const float* Wp2 = (const float*)d_in[8];
    const float* bp2 = (const float*)d_in[9];

    char* wsb = (char*)d_ws;
    size_t off = 0;
    auto alloc = [&](size_t bytes) -> void* {
        void* p = wsb + off;
        off += (bytes + 255) & ~(size_t)255;
        return p;
    };
    unsigned short* adjb  = (unsigned short*)alloc((size_t)NB * NSP * NSP * 2);   // 8 MB
    float* deg_inv        = (float*)alloc((size_t)NB * NSP * 4);
    float* spf            = (float*)alloc((size_t)NB * NSP * NC * 4);             // 4 MB
    unsigned short* spfT  = (unsigned short*)alloc((size_t)NB * NC * NSP * 2);    // 2 MB
    float* x              = (float*)alloc((size_t)NB * NSP * NC * 4);             // 4 MB
    float* z1g            = (float*)alloc((size_t)NB * NSP * OUTD * 4);
    float* z2g            = (float*)alloc((size_t)NB * NSP * OUTD * 4);
    float* row_loss       = (float*)alloc((size_t)NB * NSP * 4);
    unsigned* counts_u    = (unsigned*)alloc((size_t)NB * NSP * 4);
    unsigned* offsets     = (unsigned*)alloc((size_t)NB * (NSP + 1) * 4);
    unsigned* cursor      = (unsigned*)alloc((size_t)NB * NSP * 4);
    int* rank             = (int*)alloc((size_t)NB * NPIX * 4);                   // 1 MB
    unsigned char* featP  = (unsigned char*)alloc((size_t)NB * NPIX * NC);        // 67 MB fp8

    hipMemsetAsync(adjb, 0, (size_t)NB * NSP * NSP * 2, stream);
    hipMemsetAsync(counts_u, 0, (size_t)NB * NSP * 4, stream);

    hist_kernel<<<dim3(64, NB), 256, 0, stream>>>(idx, counts_u);
    scan_kernel<<<NB, 256, 0, stream>>>(counts_u, offsets, cursor);
    rank_kernel<<<dim3(64, NB), 256, 0, stream>>>(idx, cursor, rank);

    int total_adj = NB * (2 * 65280 + NSP);
    adj_kernel<<<(total_adj + 255) / 256, 256, 0, stream>>>(idx, adjb);
    deg_kernel<<<NB * NSP, 256, 0, stream>>>(adjb, deg_inv);

    transpose_kernel<<<dim3(NPIX / 64, NB), 256, 0, stream>>>(feat, rank, featP);
    segsum_kernel<<<dim3(NSP, NB), 256, 0, stream>>>(featP, offsets, deg_inv, spf);
    spft_kernel<<<dim3(NSP / 64, NC / 64, NB), 256, 0, stream>>>(spf, spfT);

    conv_kernel<<<dim3(NC / 64, NSP / 64, NB), 256, 0, stream>>>(adjb, spfT, deg_inv, x);
    encoder_kernel<<<NB * 64, 256, 0, stream>>>(x, W1, b1, W2, b2, Wp1, bp1, Wp2, bp2, z1g, z2g);
    infonce_kernel<<<NB * 64, 256, 0, stream>>>(z1g, z2g, row_loss);
    reduce_kernel<<<1, 256, 0, stream>>>(row_loss, (float*)d_out);
}